// Round 6
// baseline (290.489 us; speedup 1.0000x reference)
//
#include <hip/hip_runtime.h>
#include <hip/hip_bf16.h>

// Problem constants (fixed by setup_inputs)
#define NB 4
#define SEQ 2048
#define HID 768
#define NSPAN 16384            // spans per batch
#define M_TOT (NB * NSPAN)     // 65536 rows
#define K2 1536                // 2*HID
#define NTILE 24               // K2 / 64
#define CMP_CAP 66048          // compacted-table capacity
#define BM 128
#define BN 256

typedef float f32x4 __attribute__((ext_vector_type(4)));
typedef short s16x8 __attribute__((ext_vector_type(8)));
using bf16 = __hip_bfloat16;

// global -> LDS direct (16B per lane). Dest is wave-uniform base (HW adds
// lane*16); global src is per-lane (gather-capable).
__device__ __forceinline__ void gll16(const void* g, void* l) {
    __builtin_amdgcn_global_load_lds(
        (const __attribute__((address_space(1))) unsigned*)g,
        (__attribute__((address_space(3))) unsigned*)l, 16, 0, 0);
}

// ---------------------------------------------------------------------------
__global__ void mask_detect_kernel(const unsigned* __restrict__ masks, int* __restrict__ flag) {
    int t = blockIdx.x * 256 + threadIdx.x;
    if (t < 16384) {
        unsigned v = masks[t];
        if (v > 1u) atomicOr(flag, 1);   // multi-byte pattern => byte-packed bools
    }
}

__device__ __forceinline__ bool mask_at(const int* masks, int u8, int m) {
    return u8 ? (((const unsigned char*)masks)[m] != 0) : (masks[m] != 0);
}

// ---------------------------------------------------------------------------
__global__ void init_compact_kernel(int* __restrict__ cS, int* __restrict__ cE,
                                    int* __restrict__ cO) {
    int i = blockIdx.x * 256 + threadIdx.x;
    if (i < CMP_CAP) { cS[i] = 0; cE[i] = 0; cO[i] = -1; }
}

// ---------------------------------------------------------------------------
__global__ void count_kernel(const int* __restrict__ masks, const int* __restrict__ flag,
                             int* __restrict__ blockCnt) {
    int bid = blockIdx.x, tid = threadIdx.x;
    bool act = mask_at(masks, flag[0], bid * 256 + tid);
    unsigned long long b = __ballot(act);
    __shared__ int wc[4];
    if ((tid & 63) == 0) wc[tid >> 6] = __popcll(b);
    __syncthreads();
    if (tid == 0) blockCnt[bid] = wc[0] + wc[1] + wc[2] + wc[3];
}

__global__ void scan_kernel(const int* __restrict__ blockCnt, int* __restrict__ blockOff,
                            int* __restrict__ cnt) {
    __shared__ int s[256];
    int t = threadIdx.x;
    int mine = blockCnt[t];
    s[t] = mine;
    __syncthreads();
    for (int d = 1; d < 256; d <<= 1) {
        int v = (t >= d) ? s[t - d] : 0;
        __syncthreads();
        s[t] += v;
        __syncthreads();
    }
    blockOff[t] = s[t] - mine;
    if (t == 255) cnt[0] = s[255];
}

__global__ void scatter_kernel(const int* __restrict__ span_ids, const int* __restrict__ masks,
                               const int* __restrict__ flag, const int* __restrict__ pooling,
                               const int* __restrict__ blockOff,
                               int* __restrict__ cS, int* __restrict__ cE,
                               int* __restrict__ cO, int* __restrict__ cI) {
    int bid = blockIdx.x, tid = threadIdx.x;
    int m = bid * 256 + tid;
    bool act = mask_at(masks, flag[0], m);
    unsigned long long b = __ballot(act);
    __shared__ int wA[4], wI[4];
    int lane = tid & 63, w = tid >> 6;
    int wAct = __popcll(b);
    if (lane == 0) { wA[w] = wAct; wI[w] = 64 - wAct; }
    __syncthreads();
    if (tid == 0) {
        int a = 0, ii = 0;
#pragma unroll
        for (int i = 0; i < 4; ++i) {
            int ca = wA[i], ci = wI[i];
            wA[i] = a; wI[i] = ii; a += ca; ii += ci;
        }
    }
    __syncthreads();
    unsigned long long below = (lane == 63) ? ~0ULL >> 1 : ((1ULL << lane) - 1ULL);
    if (act) {
        int rank = __popcll(b & below);
        int idx = blockOff[bid] + wA[w] + rank;
        int s = span_ids[2 * m], e = span_ids[2 * m + 1];
        int bb = m >> 14;
        int window = (pooling[0] != 0) ? 1 : 3;
        int cw = min(window, e - s);
        int base = (bb * 3 + (cw - 1)) * SEQ;
        cS[idx] = base + s;
        cE[idx] = base + (e - cw);
        cO[idx] = m;
    } else {
        int rank = __popcll(~b & below);
        int idx = (bid * 256 - blockOff[bid]) + wI[w] + rank;
        cI[idx] = m;
    }
}

// ---------------------------------------------------------------------------
__global__ void prep_m3_kernel(const float* __restrict__ T, bf16* __restrict__ M3) {
    int b = blockIdx.y;
    int p0 = blockIdx.x * 16;
    int t = threadIdx.x;
    const float* Tb = T + (size_t)b * SEQ * HID;
    bf16* o0 = M3 + (size_t)(b * 3 + 0) * SEQ * HID;
    bf16* o1 = M3 + (size_t)(b * 3 + 1) * SEQ * HID;
    bf16* o2 = M3 + (size_t)(b * 3 + 2) * SEQ * HID;
#pragma unroll
    for (int c = 0; c < 3; ++c) {
        int h = t + c * 256;
        float x0 = Tb[(size_t)p0 * HID + h];
        float x1 = Tb[(size_t)min(p0 + 1, SEQ - 1) * HID + h];
        for (int i = 0; i < 16; ++i) {
            int p = p0 + i;
            float x2 = Tb[(size_t)min(p + 2, SEQ - 1) * HID + h];
            float m2 = fmaxf(x0, x1);
            float m3v = fmaxf(m2, x2);
            size_t off = (size_t)p * HID + h;
            o0[off] = __float2bfloat16(x0);
            o1[off] = __float2bfloat16(m2);
            o2[off] = __float2bfloat16(m3v);
            x0 = x1; x1 = x2;
        }
    }
}

// ---------------------------------------------------------------------------
__global__ void prep_wt_kernel(const float* __restrict__ W, bf16* __restrict__ Wt) {
    __shared__ float tile[64][65];
    int k0 = blockIdx.x * 64;
    int n0 = blockIdx.y * 64;
    int t = threadIdx.x;
    int c = t & 63, r4 = t >> 6;
    for (int r = r4; r < 64; r += 4)
        tile[r][c] = W[(size_t)(k0 + r) * HID + n0 + c];
    __syncthreads();
    for (int r = r4; r < 64; r += 4)
        Wt[(size_t)(n0 + r) * K2 + k0 + c] = __float2bfloat16(tile[c][r]);
}

// ---------------------------------------------------------------------------
// Pipelined GEMM: BM=128 x BN=256, 8 waves (2m x 4n, 64x64 each), BK=64 as
// two 32-K segments per operand. LDS = 8 slots: A 4x8KB @0, B 4x16KB @32K.
// Slot(t,kh) = ((t&1)<<1)|kh. Per phase: vmcnt-wait, barrier, issue the
// segment 3 phases ahead (3 gll16/thread), 8 ds_read_b128, 16 MFMA/wave.
// Wait derivation (3 loads/thread/phase): needed segment issued 3 phases
// back => 6 newer loads allowed in flight => vmcnt(6); tail 3/0.
// 16B-chunk XOR swizzle (chunk ^= row&3) applied on global source AND on the
// ds_read side (rule 21) -> conflict-free frag reads.
__global__ __launch_bounds__(512, 2)
void span_gemm_kernel(const bf16* __restrict__ M3, const bf16* __restrict__ Wt,
                      const int* __restrict__ cS, const int* __restrict__ cE,
                      const int* __restrict__ cO, const int* __restrict__ cI,
                      const int* __restrict__ cnt,
                      const float* __restrict__ bias, float* __restrict__ out) {
    __shared__ char lds[98304];
    __shared__ int rOs[128];

    const int tid = threadIdx.x;
    const int n0 = blockIdx.x * BN;        // 3 col strips
    const int count = cnt[0];
    const int actT = (count + BM - 1) >> 7;

    if ((int)blockIdx.y >= actT) {
        // ---- inactive fill: out[cI[r]] = bias over this 256-col strip ----
        int r = ((int)blockIdx.y - actT) * 128 + (tid >> 2);
        if (r < M_TOT - count) {
            int o = cI[r];
            int c0 = n0 + (tid & 3) * 64;
            const float* bs = bias + c0;
            float* dst = out + (size_t)o * HID + c0;
#pragma unroll
            for (int c = 0; c < 16; ++c)
                *(f32x4*)(dst + c * 4) = *(const f32x4*)(bs + c * 4);
        }
        return;
    }

    const int m0 = blockIdx.y * BM;
    if (tid < 128) rOs[tid] = cO[m0 + tid];

    const int lane = tid & 63, w = tid >> 6;
    const int wm = w >> 2, wn = w & 3;         // 2 x 4 waves
    const int lr = lane & 15, lg = lane >> 4;
    const int chunkOff = (lg ^ (lr & 3)) << 4; // read-side swizzle

    // Stage sources (source-side swizzle: chunk ^= row&3)
    const int swz = ((lane & 3) ^ ((lane >> 2) & 3)) << 4;
    const int rowA = w * 16 + (lane >> 2);                 // 0..127
    const char* srcSA = (const char*)M3 + (size_t)cS[m0 + rowA] * 1536 + swz;
    const char* srcEA = (const char*)M3 + (size_t)cE[m0 + rowA] * 1536 + swz;
    const int rowB = w * 32 + (lane >> 2);                 // q=0 row; q=1 adds 16
    const char* srcB0 = (const char*)Wt + (size_t)(n0 + rowB) * 3072 + swz;
    const char* srcB1 = srcB0 + (size_t)16 * 3072;
    const int dstA  = w * 1024;                            // + slot*8192
    const int dstB0 = 32768 + (w * 2) * 1024;              // + slot*16384
    const int dstB1 = dstB0 + 1024;

#define STAGE_SEG(T, KH) do {                                              \
        const int _t = (T), _kh = (KH);                                    \
        const int _slot = ((_t & 1) << 1) | _kh;                           \
        const int _aoff = (_t < 12 ? _t * 128 : (_t - 12) * 128) + _kh * 64;\
        const int _boff = _t * 128 + _kh * 64;                             \
        gll16((_t < 12 ? srcSA : srcEA) + _aoff, lds + _slot * 8192 + dstA);\
        gll16(srcB0 + _boff, lds + _slot * 16384 + dstB0);                 \
        gll16(srcB1 + _boff, lds + _slot * 16384 + dstB1);                 \
    } while (0)

#define COMPUTE(DB, KH) do {                                               \
        const int _slot = ((DB) << 1) | (KH);                              \
        const char* _la = lds + _slot * 8192;                              \
        const char* _lb = lds + 32768 + _slot * 16384;                     \
        s16x8 _bfr[4];                                                     \
        _Pragma("unroll")                                                  \
        for (int _j = 0; _j < 4; ++_j)                                     \
            _bfr[_j] = *(const s16x8*)(_lb + (wn * 64 + _j * 16 + lr) * 64 + chunkOff); \
        _Pragma("unroll")                                                  \
        for (int _i = 0; _i < 4; ++_i) {                                   \
            s16x8 _af = *(const s16x8*)(_la + (wm * 64 + _i * 16 + lr) * 64 + chunkOff); \
            _Pragma("unroll")                                              \
            for (int _j = 0; _j < 4; ++_j)                                 \
                acc[_i][_j] = __builtin_amdgcn_mfma_f32_16x16x32_bf16(_af, _bfr[_j], acc[_i][_j], 0, 0, 0); \
        }                                                                  \
    } while (0)

#define WAITV(N) asm volatile("s_waitcnt vmcnt(" #N ")" ::: "memory")
#define BARRIER() do { __builtin_amdgcn_sched_barrier(0);                  \
        __builtin_amdgcn_s_barrier();                                      \
        asm volatile("" ::: "memory");                                     \
        __builtin_amdgcn_sched_barrier(0); } while (0)

    f32x4 acc[4][4];
#pragma unroll
    for (int i = 0; i < 4; i++)
#pragma unroll
        for (int j = 0; j < 4; j++) acc[i][j] = (f32x4){0.f, 0.f, 0.f, 0.f};

    // Prologue: k0(0), k1(0), k0(1)  (9 loads/thread)
    STAGE_SEG(0, 0);
    STAGE_SEG(0, 1);
    STAGE_SEG(1, 0);

    for (int u = 0; u < NTILE; ++u) {
        const int db = u & 1;
        // ---- phase A: kh=0 of tile u ----
        if (u < NTILE - 1) { WAITV(6); } else { WAITV(3); }
        BARRIER();
        if (u + 1 < NTILE) STAGE_SEG(u + 1, 1);   // k1 segs of tile u+1
        __builtin_amdgcn_s_setprio(1);
        COMPUTE(db, 0);
        __builtin_amdgcn_s_setprio(0);
        // ---- phase C: kh=1 of tile u ----
        if (u < NTILE - 1) { WAITV(6); } else { WAITV(0); }
        BARRIER();
        if (u + 2 < NTILE) STAGE_SEG(u + 2, 0);   // k0 segs of tile u+2
        __builtin_amdgcn_s_setprio(1);
        COMPUTE(db, 1);
        __builtin_amdgcn_s_setprio(0);
    }
#undef STAGE_SEG
#undef COMPUTE
#undef WAITV
#undef BARRIER

    // Epilogue: C/D layout (verified m89): col = lane&15, row = (lane>>4)*4+q
#pragma unroll
    for (int i = 0; i < 4; i++) {
#pragma unroll
        for (int j = 0; j < 4; j++) {
#pragma unroll
            for (int q = 0; q < 4; q++) {
                int mloc = wm * 64 + i * 16 + lg * 4 + q;
                int o = rOs[mloc];
                if (o >= 0) {
                    int n = n0 + wn * 64 + j * 16 + lr;
                    out[(size_t)o * HID + n] = acc[i][j][q] + bias[n];
                }
            }
        }
    }
}

// ---------------------------------------------------------------------------
extern "C" void kernel_launch(void* const* d_in, const int* in_sizes, int n_in,
                              void* d_out, int out_size, void* d_ws, size_t ws_size,
                              hipStream_t stream) {
    const float* token_reps = (const float*)d_in[0];
    const int*   span_ids   = (const int*)d_in[1];
    const int*   span_masks = (const int*)d_in[2];
    const int*   pooling    = (const int*)d_in[3];
    const float* W          = (const float*)d_in[4];
    const float* bias       = (const float*)d_in[5];
    float* out = (float*)d_out;

    char* ws = (char*)d_ws;
    int*  flag = (int*)ws;
    int*  cnt  = (int*)(ws + 4);
    int*  blockCnt = (int*)(ws + 1024);
    int*  blockOff = (int*)(ws + 2048);
    int*  cS   = (int*)(ws + 4096);
    int*  cE   = (int*)(ws + 4096 + 4 * CMP_CAP);
    int*  cO   = (int*)(ws + 4096 + 8 * CMP_CAP);
    int*  cI   = (int*)(ws + 4096 + 12 * CMP_CAP);
    bf16* M3   = (bf16*)(ws + (2 << 20));
    const size_t M3_BYTES = (size_t)NB * 3 * SEQ * HID * 2;   // 37,748,736
    bf16* Wt   = (bf16*)(ws + (2 << 20) + M3_BYTES);

    hipMemsetAsync(ws, 0, 64, stream);
    mask_detect_kernel<<<64, 256, 0, stream>>>((const unsigned*)span_masks, flag);
    init_compact_kernel<<<(CMP_CAP + 255) / 256, 256, 0, stream>>>(cS, cE, cO);
    count_kernel<<<M_TOT / 256, 256, 0, stream>>>(span_masks, flag, blockCnt);
    scan_kernel<<<1, 256, 0, stream>>>(blockCnt, blockOff, cnt);
    scatter_kernel<<<M_TOT / 256, 256, 0, stream>>>(span_ids, span_masks, flag, pooling,
                                                    blockOff, cS, cE, cO, cI);
    prep_m3_kernel<<<dim3(SEQ / 16, NB), 256, 0, stream>>>(token_reps, M3);
    prep_wt_kernel<<<dim3(K2 / 64, HID / 64), 256, 0, stream>>>(W, Wt);
    span_gemm_kernel<<<dim3(HID / BN, 516), 512, 0, stream>>>(
        M3, Wt, cS, cE, cO, cI, cnt, bias, out);
}